// Round 2
// baseline (239.354 us; speedup 1.0000x reference)
//
#include <hip/hip_runtime.h>

// 3D spatial transformer (trilinear warp), voxelmorph semantics.
// vol: [B=2, X=160, Y=192, Z=160, C=1] fp32
// trf: [B=2, X=160, Y=192, Z=160, 3]  fp32 (dense displacement)
// out: same shape as vol, fp32.
//
// R6: (a) z-STRIDED voxel ownership (thread's voxel j at z = z0t + zq + 4j):
// within one ds_read instruction the lanes now span z&3 = 0..3, so bank bits
// 0-1 vary; combined with the bits-2-4 XOR swizzle the wave spreads over all
// 32 banks at 2 lanes/bank (free). The old consecutive-z mapping pinned
// z ≡ j (mod 4) wave-wide -> at most 8 banks -> 8-way conflict (the measured
// 6.2M residual). (b) all address/weight math hoisted BEFORE the barrier so
// it overlaps the global_load_lds drain; post-barrier is just ds_read+blend.
// trf loads are issued before staging so prep's waitcnt leaves staging in
// flight. Fallback (outside staged window, ~0.1%) reloads trf cold.

#define NXD 160
#define NYD 192
#define NZD 160
#define NVOX (NXD * NYD * NZD)
#define NBATCH 2

#define TXT 8
#define TYT 16
#define TZT 16
#define LXT 16            // staged x extent
#define LYT 24            // staged y extent
#define LZT 32            // staged z extent
#define LDS_N (LXT * LYT * LZT)   // 12288 floats = 48 KB

#define TILES_X (NXD / TXT)   // 20
#define TILES_Y (NYD / TYT)   // 12
#define TILES_Z (NZD / TZT)   // 10
#define NBLOCKS (NBATCH * TILES_X * TILES_Y * TILES_Z)   // 4800

__global__ __launch_bounds__(512)
void warp3d_kernel(const float* __restrict__ vol,
                   const float* __restrict__ trf,
                   float* __restrict__ out) {
    __shared__ float tile[LDS_N];

    int bid = blockIdx.x;
    int tz = bid % TILES_Z;
    int r  = bid / TILES_Z;
    int ty = r % TILES_Y;
    int r2 = r / TILES_Y;
    int tx = r2 % TILES_X;
    int b  = r2 / TILES_X;

    int x0t = tx * TXT, y0t = ty * TYT, z0t = tz * TZT;
    // clamped staging origin: window always fully inside the volume
    int lox = min(max(x0t - 4, 0), NXD - LXT);
    int loy = min(max(y0t - 4, 0), NYD - LYT);
    int loz = min(max(z0t - 8, 0), NZD - LZT);

    const float* vb = vol + (size_t)b * NVOX;

    int t = threadIdx.x;
    // z-strided ownership: thread's voxel j is (x, y, z0t + zq + 4j)
    int zq = t & 3;
    int yq = (t >> 2) & 15;
    int xq = t >> 6;             // == wave id
    int x = x0t + xq, y = y0t + yq;
    int zb0 = z0t + zq;
    size_t rowi = (((size_t)b * NXD + x) * NYD + y) * NZD + zb0;
    const float* tp = trf + rowi * 3;

    // ---- trf loads FIRST (12 dwords; wave-coalesced 48B per 4-lane group) ----
    float dxa[4], dya[4], dza[4];
#pragma unroll
    for (int j = 0; j < 4; ++j) {
        dxa[j] = tp[j * 12 + 0];
        dya[j] = tp[j * 12 + 1];
        dza[j] = tp[j * 12 + 2];
    }

    // ---- stage vol tile into LDS (48 chunks x 256 floats, async 16B) ----
    {
        const float* gbase = vb + ((size_t)(lox * NYD + loy) * NZD + loz);
        int w = t >> 6;                  // wave id 0..7
        int l = t & 63;                  // lane
        int zgrp = (l & 7) << 2;         // slot z-group base within the 32-row
        int lrow = l >> 3;               // 0..7: y-row index within chunk
#pragma unroll
        for (int it = 0; it < 6; ++it) {
            int chunk = it * 8 + w;          // 0..47, wave-uniform
            int rest = chunk * 8 + lrow;     // linear (x,y) row index
            int yi = rest % LYT;
            int xi = rest / LYT;
            // inverse swizzle on the SOURCE z (XOR is an involution)
            int sz = zgrp ^ ((yi & 7) << 2);
            const float* g = gbase + (size_t)xi * (NYD * NZD) + yi * NZD + sz;
            __builtin_amdgcn_global_load_lds(
                (const __attribute__((address_space(1))) void*)g,
                (__attribute__((address_space(3))) void*)&tile[chunk * 256],
                16, 0, 0);
        }
    }

    // ---- prep: all address/weight math, overlapped with staging drain ----
    int A[4], B[4], C[4], D[4];
    float WX[4], WY[4], WZ[4];
    int okbits = 0;
#pragma unroll
    for (int j = 0; j < 4; ++j) {
        float lx = fminf(fmaxf((float)x + dxa[j], 0.0f), (float)(NXD - 1));
        float ly = fminf(fmaxf((float)y + dya[j], 0.0f), (float)(NYD - 1));
        float lz = fminf(fmaxf((float)(zb0 + 4 * j) + dza[j], 0.0f), (float)(NZD - 1));
        float fx = floorf(lx), fy = floorf(ly), fz = floorf(lz);
        int x0 = (int)fx, y0 = (int)fy, z0 = (int)fz;
        // lower-corner weights d1 = loc1 - loc (0 at clamped top border)
        WX[j] = fminf(fx + 1.0f, (float)(NXD - 1)) - lx;
        WY[j] = fminf(fy + 1.0f, (float)(NYD - 1)) - ly;
        WZ[j] = fminf(fz + 1.0f, (float)(NZD - 1)) - lz;
        int ix = x0 - lox, iy = y0 - loy, iz = z0 - loz;
        bool ok = ((unsigned)ix <= LXT - 2) & ((unsigned)iy <= LYT - 2) &
                  ((unsigned)iz <= LZT - 2);
        okbits |= ((int)ok) << j;
        int sx = ok ? ix : 0;
        int sy = ok ? iy : 0;
        int sv = ok ? iz : 0;
        int base = (sx * LYT + sy) * LZT;
        int sw0 = (sy & 7) << 2;
        int sw1 = ((sy + 1) & 7) << 2;
        A[j] = base + (sv ^ sw0);
        B[j] = base + ((sv + 1) ^ sw0);
        C[j] = base + (sv ^ sw1);
        D[j] = base + ((sv + 1) ^ sw1);
    }
    __syncthreads();

    // ---- gather + trilinear blend, 4 voxels ----
#pragma unroll
    for (int j = 0; j < 4; ++j) {
        float v000 = tile[A[j]],                  v001 = tile[B[j]];
        float v010 = tile[C[j] + LZT],            v011 = tile[D[j] + LZT];
        float v100 = tile[A[j] + LYT * LZT],      v101 = tile[B[j] + LYT * LZT];
        float v110 = tile[C[j] + LYT * LZT + LZT], v111 = tile[D[j] + LYT * LZT + LZT];

        if (!((okbits >> j) & 1)) {   // rare: outside staged window -> global
            float dx = tp[j * 12 + 0];
            float dy = tp[j * 12 + 1];
            float dz = tp[j * 12 + 2];
            float lx = fminf(fmaxf((float)x + dx, 0.0f), (float)(NXD - 1));
            float ly = fminf(fmaxf((float)y + dy, 0.0f), (float)(NYD - 1));
            float lz = fminf(fmaxf((float)(zb0 + 4 * j) + dz, 0.0f), (float)(NZD - 1));
            int x0 = (int)floorf(lx), y0 = (int)floorf(ly), z0 = (int)floorf(lz);
            int x1 = min(x0 + 1, NXD - 1);
            int y1 = min(y0 + 1, NYD - 1);
            int z1 = min(z0 + 1, NZD - 1);
            size_t o00 = (size_t)(x0 * NYD + y0) * NZD;
            size_t o01 = (size_t)(x0 * NYD + y1) * NZD;
            size_t o10 = (size_t)(x1 * NYD + y0) * NZD;
            size_t o11 = (size_t)(x1 * NYD + y1) * NZD;
            v000 = vb[o00 + z0]; v001 = vb[o00 + z1];
            v010 = vb[o01 + z0]; v011 = vb[o01 + z1];
            v100 = vb[o10 + z0]; v101 = vb[o10 + z1];
            v110 = vb[o11 + z0]; v111 = vb[o11 + z1];
        }

        float wx0 = WX[j], wy0 = WY[j], wz0 = WZ[j];
        float wx1 = 1.0f - wx0, wy1 = 1.0f - wy0, wz1 = 1.0f - wz0;
        float res = wx0 * (wy0 * (wz0 * v000 + wz1 * v001) +
                           wy1 * (wz0 * v010 + wz1 * v011)) +
                    wx1 * (wy0 * (wz0 * v100 + wz1 * v101) +
                           wy1 * (wz0 * v110 + wz1 * v111));
        // store: lanes zq=0..3 write consecutive dwords; the wave's 4 stores
        // fully cover each row's 64B segment -> coalesced, no RFO growth
        out[rowi + 4 * j] = res;
    }
}

extern "C" void kernel_launch(void* const* d_in, const int* in_sizes, int n_in,
                              void* d_out, int out_size, void* d_ws, size_t ws_size,
                              hipStream_t stream) {
    const float* vol = (const float*)d_in[0];
    const float* trf = (const float*)d_in[1];
    float* out = (float*)d_out;

    warp3d_kernel<<<NBLOCKS, 512, 0, stream>>>(vol, trf, out);
}